// Round 7
// baseline (72.497 us; speedup 1.0000x reference)
//
#include <hip/hip_runtime.h>

// SqueezeExcitation: x[32,256,64,64] f32, W1[64,256], b1[64], W2[256,64], b2[256]
// y = x * hardsigmoid( relu( mean_hw(x) @ W1^T + b1 ) @ W2^T + b2 )
// SINGLE persistent kernel, ONE pass over x from HBM:
//   512 blocks x 512 thr (8 waves). __launch_bounds__(512,4) => VGPR<=128 =>
//   2 blocks/CU => all 512 blocks co-resident (256 CUs) => spin-sync is safe.
//   Block owns (batch b, 16 channels) = 256 KiB = 32 f32x4/thread:
//     20 f32x4 in registers + 7 f32x4 in LDS (56 KiB) + 5 f32x4 re-read (L3).
//   Phase 1: stream chunk, per-channel means (deterministic tree), publish
//            m[], release-add padded per-batch counter (16 adds/counter).
//   Sync:    leader acquire-spins until counter==16 (agent scope).
//   Phase 2: per-block gate (coalesced W1/W2, round-5 pattern), scale+nt-store.
// Lessons: r2: no contended atomics (256+/line serializes ~50ns each);
//          r4: redundant work must be coalesced & small; r6: cross-kernel L3
//          reuse caps at ~50% -> keep x on-chip instead.

#define SE_B  32
#define SE_C  256
#define SE_SQ 64
#define SE_HW 4096      // 64*64
#define CPB   16        // channels per block
#define TPB   512       // threads per block (8 waves)
#define VPT   32        // f32x4 per thread (16 ch * 1024 f32x4 / 512 thr)
#define N_RE  5         // re-read from cache
#define N_LDS 7         // held in LDS   (7*512*16B = 56 KiB)
#define N_REG 20        // held in VGPRs (80 regs data)
#define RDY_STRIDE 32   // ints; 128B pad per batch counter

typedef float f32x4 __attribute__((ext_vector_type(4)));

__device__ __forceinline__ float hsig(float v) {
    return fminf(fmaxf(v * (1.0f / 6.0f) + 0.5f, 0.0f), 1.0f);
}

__global__ __launch_bounds__(TPB, 4) void se_fused_kernel(
    const float* __restrict__ x,
    const float* __restrict__ W1, const float* __restrict__ b1,
    const float* __restrict__ W2, const float* __restrict__ b2,
    float* __restrict__ m, int* __restrict__ ready,
    float* __restrict__ y) {
    const int blk  = blockIdx.x;
    const int b    = blk >> 4;
    const int c0   = (blk & 15) * CPB;
    const int t    = threadIdx.x;
    const int wave = t >> 6;             // 0..7
    const int lane = t & 63;

    __shared__ f32x4 ldsdata[N_LDS * TPB];   // 56 KiB
    __shared__ float partials[CPB * 8];      // [ch][wave]
    __shared__ f32x4 m4_lds[SE_C / 4];
    __shared__ float s_lds[SE_SQ];
    __shared__ float g_lds[CPB];

    const size_t base = ((size_t)b * SE_C + c0) * (SE_HW / 4);
    const f32x4* xv = reinterpret_cast<const f32x4*>(x) + base;
    f32x4*       yv = reinterpret_cast<f32x4*>(y)       + base;

    // ---------------- Phase 1: stream chunk once; channel sums -------------
    f32x4 keep[N_REG];
    float part = 0.0f;                   // channel = k>>1 (1024 f32x4/ch)
#pragma unroll
    for (int k = 0; k < VPT; ++k) {
        f32x4 v = xv[k * TPB + t];
        if (k >= N_RE && k < N_RE + N_LDS) ldsdata[(k - N_RE) * TPB + t] = v;
        if (k >= N_RE + N_LDS)             keep[k - (N_RE + N_LDS)] = v;
        part += (v.x + v.y) + (v.z + v.w);
        if (k & 1) {
            float p = part;
#pragma unroll
            for (int off = 1; off < 64; off <<= 1) p += __shfl_xor(p, off);
            if (lane == 0) partials[(k >> 1) * 8 + wave] = p;
            part = 0.0f;
        }
    }
    __syncthreads();

    // deterministic final reduce: thread c (<16) sums its 8 wave partials
    if (t < CPB) {
        float s = 0.0f;
#pragma unroll
        for (int w = 0; w < 8; ++w) s += partials[t * 8 + w];
        m[b * SE_C + c0 + t] = s * (1.0f / SE_HW);
    }
    __syncthreads();                     // all m-stores issued (drained at barrier)

    // ---------------- publish + per-batch sync (16 blocks/batch) -----------
    if (t == 0) {
        __hip_atomic_fetch_add(&ready[b * RDY_STRIDE], 1,
                               __ATOMIC_RELEASE, __HIP_MEMORY_SCOPE_AGENT);
        while (__hip_atomic_load(&ready[b * RDY_STRIDE],
                                 __ATOMIC_ACQUIRE, __HIP_MEMORY_SCOPE_AGENT) < CPB)
            __builtin_amdgcn_s_sleep(2);
    }
    __syncthreads();

    // ---------------- gate for this block's 16 channels --------------------
    if (t < SE_C / 4)
        m4_lds[t] = reinterpret_cast<const f32x4*>(m + b * SE_C)[t];
    __syncthreads();

    const f32x4* W1v = reinterpret_cast<const f32x4*>(W1);
    const f32x4 mv = m4_lds[lane];
#pragma unroll
    for (int i = 0; i < 8; ++i) {        // wave w owns o = 8w..8w+7
        const int o = wave * 8 + i;
        f32x4 w4 = W1v[o * 64 + lane];   // coalesced row read
        float p = w4.x * mv.x;
        p = fmaf(w4.y, mv.y, p);
        p = fmaf(w4.z, mv.z, p);
        p = fmaf(w4.w, mv.w, p);
#pragma unroll
        for (int off = 1; off < 64; off <<= 1) p += __shfl_xor(p, off);
        if (lane == 0) s_lds[o] = fmaxf(p + b1[o], 0.0f);
    }
    __syncthreads();

#pragma unroll
    for (int i = 0; i < 2; ++i) {        // wave w owns channels 2w, 2w+1
        const int cl = wave * 2 + i;
        const int c  = c0 + cl;
        float p = W2[c * SE_SQ + lane] * s_lds[lane];
#pragma unroll
        for (int off = 1; off < 64; off <<= 1) p += __shfl_xor(p, off);
        if (lane == 0) g_lds[cl] = hsig(p + b2[c]);
    }
    __syncthreads();

    // ---------------- Phase 2: scale + nontemporal store -------------------
#pragma unroll
    for (int k = 0; k < VPT; ++k) {
        const float g = g_lds[k >> 1];
        f32x4 v;
        if (k < N_RE)                 v = xv[k * TPB + t];            // L3
        else if (k < N_RE + N_LDS)    v = ldsdata[(k - N_RE) * TPB + t];
        else                          v = keep[k - (N_RE + N_LDS)];
        v *= g;
        __builtin_nontemporal_store(v, &yv[k * TPB + t]);
    }
}

extern "C" void kernel_launch(void* const* d_in, const int* in_sizes, int n_in,
                              void* d_out, int out_size, void* d_ws, size_t ws_size,
                              hipStream_t stream) {
    const float* x  = (const float*)d_in[0];
    const float* W1 = (const float*)d_in[1];
    const float* b1 = (const float*)d_in[2];
    const float* W2 = (const float*)d_in[3];
    const float* b2 = (const float*)d_in[4];
    float* y = (float*)d_out;

    float* m     = (float*)d_ws;                     // B*C floats
    int*   ready = (int*)(m + SE_B * SE_C);          // B*RDY_STRIDE ints

    hipMemsetAsync(ready, 0, SE_B * RDY_STRIDE * sizeof(int), stream);
    se_fused_kernel<<<SE_B * (SE_C / CPB), TPB, 0, stream>>>(
        x, W1, b1, W2, b2, m, ready, y);
}